// Round 4
// baseline (663.796 us; speedup 1.0000x reference)
//
#include <hip/hip_runtime.h>
#include <hip/hip_bf16.h>

#define NN 100000
#define NE 1600000
#define NG 512
#define NC 10

typedef __attribute__((ext_vector_type(8))) short bf16x8;
typedef __attribute__((ext_vector_type(4))) float f32x4;

__device__ __forceinline__ float bflo(unsigned u) { return __uint_as_float(u << 16); }
__device__ __forceinline__ float bfhi(unsigned u) { return __uint_as_float(u & 0xffff0000u); }
__device__ __forceinline__ unsigned short f2bf(float f) {
  unsigned u = __float_as_uint(f);
  unsigned r = u + 0x7fffu + ((u >> 16) & 1u);
  return (unsigned short)(r >> 16);
}

// ---------------- preprocessing: degree, dinv, CSR (AoS) by dst ----------------

__global__ __launch_bounds__(256) void k_deg(const int* __restrict__ dst, int* __restrict__ deg) {
  int e = blockIdx.x * 256 + threadIdx.x;
  if (e < NE) atomicAdd(&deg[dst[e]], 1);
}

__global__ __launch_bounds__(256) void k_dinv(const int* __restrict__ deg, float* __restrict__ dinv) {
  int i = blockIdx.x * 256 + threadIdx.x;
  if (i < NN) dinv[i] = rsqrtf((float)deg[i] + 1.0f);
}

__global__ __launch_bounds__(256) void k_bsum(const int* __restrict__ deg, int* __restrict__ bsum) {
  __shared__ int sm[256];
  int i = blockIdx.x * 256 + threadIdx.x;
  sm[threadIdx.x] = (i < NN) ? deg[i] : 0;
  __syncthreads();
  for (int o = 128; o > 0; o >>= 1) {
    if (threadIdx.x < o) sm[threadIdx.x] += sm[threadIdx.x + o];
    __syncthreads();
  }
  if (threadIdx.x == 0) bsum[blockIdx.x] = sm[0];
}

// parallel exclusive scan of bsum (nb <= 512), one block of 512 threads
__global__ __launch_bounds__(512) void k_scan_par(int* bsum, int nb) {
  __shared__ int sm[512];
  int t = threadIdx.x;
  int orig = (t < nb) ? bsum[t] : 0;
  sm[t] = orig;
  __syncthreads();
  for (int o = 1; o < 512; o <<= 1) {
    int v = (t >= o) ? sm[t - o] : 0;
    __syncthreads();
    sm[t] += v;
    __syncthreads();
  }
  if (t < nb) bsum[t] = sm[t] - orig;  // exclusive
}

__global__ __launch_bounds__(256) void k_offs(const int* __restrict__ deg, const int* __restrict__ bsum,
                                              int* __restrict__ offs) {
  __shared__ int sm[256];
  int i = blockIdx.x * 256 + threadIdx.x;
  int v = (i < NN) ? deg[i] : 0;
  sm[threadIdx.x] = v;
  __syncthreads();
  for (int o = 1; o < 256; o <<= 1) {
    int t = (threadIdx.x >= o) ? sm[threadIdx.x - o] : 0;
    __syncthreads();
    sm[threadIdx.x] += t;
    __syncthreads();
  }
  if (i < NN) offs[i] = bsum[blockIdx.x] + sm[threadIdx.x] - v;  // exclusive
}

__global__ __launch_bounds__(256) void k_csr(const int* __restrict__ src, const int* __restrict__ dst,
                                             const int* __restrict__ offs, int* __restrict__ cursor,
                                             const float* __restrict__ dinv,
                                             int2* __restrict__ csr) {
  int e = blockIdx.x * 256 + threadIdx.x;
  if (e < NE) {
    int s = src[e], d = dst[e];
    int p = offs[d] + atomicAdd(&cursor[d], 1);
    int2 v;
    v.x = s;
    v.y = __float_as_int(dinv[s] * dinv[d]);
    csr[p] = v;
  }
}

// Wt[c][k] = bf16(W[k][c])  (128x128)
__global__ __launch_bounds__(256) void k_wt(const float* __restrict__ W, unsigned short* __restrict__ Wt) {
  int idx = blockIdx.x * 256 + threadIdx.x;
  int k = idx >> 7, c = idx & 127;
  Wt[c * 128 + k] = f2bf(W[k * 128 + c]);
}

// ---------------- bf16 MFMA GEMM: Out[M,128] = A[M,128] @ W[128,128] ----------------

template<int ADD_BIAS, int RELU, int SRC_F32>
__global__ __launch_bounds__(256) void k_gemm_mfma(const void* __restrict__ Ap,
                                                   const unsigned short* __restrict__ Wt,
                                                   const float* __restrict__ bias,
                                                   unsigned short* __restrict__ Out, int M) {
  __shared__ uint4 Al4[2048];  // 128 rows x 16 chunks (16B = 8 bf16)
  __shared__ uint4 Wl4[2048];
  int row0 = blockIdx.x * 128;
  const uint4* W16 = (const uint4*)Wt;
#pragma unroll
  for (int it = 0; it < 8; ++it) {
    int idx = it * 256 + threadIdx.x;
    int r = idx >> 4, c = idx & 15;
    int gr = row0 + r;
    uint4 v = make_uint4(0, 0, 0, 0);
    if (gr < M) {
      if (SRC_F32) {
        const float4* Af = (const float4*)Ap;
        float4 f0 = Af[(size_t)gr * 32 + c * 2];
        float4 f1 = Af[(size_t)gr * 32 + c * 2 + 1];
        v.x = (unsigned)f2bf(f0.x) | ((unsigned)f2bf(f0.y) << 16);
        v.y = (unsigned)f2bf(f0.z) | ((unsigned)f2bf(f0.w) << 16);
        v.z = (unsigned)f2bf(f1.x) | ((unsigned)f2bf(f1.y) << 16);
        v.w = (unsigned)f2bf(f1.z) | ((unsigned)f2bf(f1.w) << 16);
      } else {
        v = ((const uint4*)Ap)[(size_t)gr * 16 + c];
      }
    }
    Al4[r * 16 + (c ^ (r & 15))] = v;
    Wl4[r * 16 + (c ^ (r & 15))] = W16[idx];
  }
  __syncthreads();

  int lane = threadIdx.x & 63;
  int wid = threadIdx.x >> 6;
  int wr = wid >> 1, wc = wid & 1;
  int lr = lane & 15, kb = lane >> 4;

  f32x4 acc[4][4] = {};
#pragma unroll
  for (int ks = 0; ks < 4; ++ks) {
    int c = ks * 4 + kb;
    bf16x8 af[4], bfr[4];
#pragma unroll
    for (int i = 0; i < 4; ++i) {
      int ar = wr * 64 + i * 16 + lr;
      af[i] = *(const bf16x8*)&Al4[ar * 16 + (c ^ lr)];
      int bc = wc * 64 + i * 16 + lr;
      bfr[i] = *(const bf16x8*)&Wl4[bc * 16 + (c ^ lr)];
    }
#pragma unroll
    for (int i = 0; i < 4; ++i)
#pragma unroll
      for (int n = 0; n < 4; ++n)
        acc[i][n] = __builtin_amdgcn_mfma_f32_16x16x32_bf16(af[i], bfr[n], acc[i][n], 0, 0, 0);
  }

  float bcol[4];
  if (ADD_BIAS) {
#pragma unroll
    for (int n = 0; n < 4; ++n) bcol[n] = bias[wc * 64 + n * 16 + lr];
  }
#pragma unroll
  for (int i = 0; i < 4; ++i) {
    int rbase = row0 + wr * 64 + i * 16 + kb * 4;
#pragma unroll
    for (int n = 0; n < 4; ++n) {
      int col = wc * 64 + n * 16 + lr;
#pragma unroll
      for (int j = 0; j < 4; ++j) {
        int gr = rbase + j;
        if (gr < M) {
          float v = acc[i][n][j];
          if (ADD_BIAS) v += bcol[n];
          if (RELU) v = fmaxf(v, 0.f);
          Out[(size_t)gr * 128 + col] = f2bf(v);
        }
      }
    }
  }
}

// ---------------- edge aggregation v2: feature-half split + edge pairing ----------------
// Half-row = 128 B = one L2 line. Lanes 0-31: edge p, lanes 32-63: edge p+1.
// out[i, half] = relu( sum_e hp[src, half]*norm + hp[i, half]*dinv_i^2 + b )

__global__ __launch_bounds__(256) void k_agg2(const unsigned short* __restrict__ hp,
                                              const int* __restrict__ offs, const int* __restrict__ deg,
                                              const float* __restrict__ dinv,
                                              const int2* __restrict__ csr,
                                              const float* __restrict__ bias,
                                              unsigned short* __restrict__ out, int half) {
  int node = blockIdx.x * 4 + (threadIdx.x >> 6);
  if (node >= NN) return;
  int l = threadIdx.x & 63;
  int li = l & 31;       // u32 col within half-row
  int up = l >> 5;       // 0: even edge of pair, 1: odd edge
  const unsigned* hp32 = (const unsigned*)hp;
  int colbase = half * 32;
  size_t cb = colbase + li;

  float di = dinv[node];
  unsigned us = hp32[(size_t)node * 64 + cb];
  float sw = up ? 0.f : di * di;
  float ax = bflo(us) * sw, ay = bfhi(us) * sw;

  int p0 = offs[node], n = deg[node];
  int p = 0;
  // main: 8 pairs = 16 edges in flight
  for (; p + 16 <= n; p += 16) {
    int2 r[8];
#pragma unroll
    for (int j = 0; j < 8; ++j) r[j] = csr[p0 + p + 2 * j + up];
    unsigned u[8];
#pragma unroll
    for (int j = 0; j < 8; ++j) u[j] = hp32[(size_t)r[j].x * 64 + cb];
#pragma unroll
    for (int j = 0; j < 8; ++j) {
      float w = __int_as_float(r[j].y);
      ax += bflo(u[j]) * w;
      ay += bfhi(u[j]) * w;
    }
  }
  // mid: 2 pairs = 4 edges
  for (; p + 4 <= n; p += 4) {
    int2 r0 = csr[p0 + p + up], r1 = csr[p0 + p + 2 + up];
    unsigned u0 = hp32[(size_t)r0.x * 64 + cb];
    unsigned u1 = hp32[(size_t)r1.x * 64 + cb];
    float w0 = __int_as_float(r0.y), w1 = __int_as_float(r1.y);
    ax += bflo(u0) * w0 + bflo(u1) * w1;
    ay += bfhi(u0) * w0 + bfhi(u1) * w1;
  }
  // tail: masked pair
  for (; p < n; p += 2) {
    int e = p + up;
    int valid = e < n;
    int2 r0 = valid ? csr[p0 + e] : make_int2(node, 0);
    unsigned u0 = hp32[(size_t)r0.x * 64 + cb];
    float w0 = valid ? __int_as_float(r0.y) : 0.f;
    ax += bflo(u0) * w0;
    ay += bfhi(u0) * w0;
  }

  ax += __shfl_xor(ax, 32);
  ay += __shfl_xor(ay, 32);
  if (!up) {
    float2 b2 = ((const float2*)bias)[colbase + li];
    ax = fmaxf(ax + b2.x, 0.f);
    ay = fmaxf(ay + b2.y, 0.f);
    ((unsigned*)out)[(size_t)node * 64 + cb] = (unsigned)f2bf(ax) | ((unsigned)f2bf(ay) << 16);
  }
}

// ---------------- pooling over sorted batch + small MLP ----------------

__device__ __forceinline__ int lowerb(const int* a, int n, int key) {
  int lo = 0, hi = n;
  while (lo < hi) {
    int mid = (lo + hi) >> 1;
    if (a[mid] < key) lo = mid + 1; else hi = mid;
  }
  return lo;
}

__global__ __launch_bounds__(128) void k_pool(const unsigned short* __restrict__ h, const int* __restrict__ batch,
                                              float* __restrict__ g) {
  int gi = blockIdx.x, d = threadIdx.x;
  int lo = lowerb(batch, NN, gi), hi = lowerb(batch, NN, gi + 1);
  float acc = 0.f;
  for (int i = lo; i < hi; ++i) acc += bflo((unsigned)h[i * 128 + d]);
  g[gi * 128 + d] = acc;
}

// small f32 GEMM for t1 = relu(g @ Wr1 + br1): M=512
__global__ __launch_bounds__(256) void k_gemm_f32(const float* __restrict__ A, const float* __restrict__ W,
                                                  const float* __restrict__ bias, float* __restrict__ Out,
                                                  int M) {
  __shared__ float4 Wl[128 * 32];
  __shared__ float4 Xl[128 * 32];
  const float4* W4 = (const float4*)W;
  for (int i = threadIdx.x; i < 4096; i += 256) Wl[i] = W4[i];
  int row0 = blockIdx.x * 128;
  const float4* A4 = (const float4*)A;
  for (int i = threadIdx.x; i < 4096; i += 256) {
    int r = i >> 5, g = i & 31;
    int gr = row0 + r;
    float4 v = make_float4(0.f, 0.f, 0.f, 0.f);
    if (gr < M) v = A4[gr * 32 + g];
    Xl[r * 32 + (g ^ ((r >> 3) & 7))] = v;
  }
  __syncthreads();

  int cg = threadIdx.x & 15;
  int rg = threadIdx.x >> 4;
  int swz = rg & 7;
  float acc[8][8] = {};
  for (int g = 0; g < 32; ++g) {
    float4 xv[8];
#pragma unroll
    for (int i = 0; i < 8; ++i) xv[i] = Xl[(rg * 8 + i) * 32 + (g ^ swz)];
#pragma unroll
    for (int kk = 0; kk < 4; ++kk) {
      float4 wa = Wl[(g * 4 + kk) * 32 + cg * 2];
      float4 wb = Wl[(g * 4 + kk) * 32 + cg * 2 + 1];
#pragma unroll
      for (int i = 0; i < 8; ++i) {
        float x = (kk == 0) ? xv[i].x : (kk == 1) ? xv[i].y : (kk == 2) ? xv[i].z : xv[i].w;
        acc[i][0] = fmaf(x, wa.x, acc[i][0]);
        acc[i][1] = fmaf(x, wa.y, acc[i][1]);
        acc[i][2] = fmaf(x, wa.z, acc[i][2]);
        acc[i][3] = fmaf(x, wa.w, acc[i][3]);
        acc[i][4] = fmaf(x, wb.x, acc[i][4]);
        acc[i][5] = fmaf(x, wb.y, acc[i][5]);
        acc[i][6] = fmaf(x, wb.z, acc[i][6]);
        acc[i][7] = fmaf(x, wb.w, acc[i][7]);
      }
    }
  }
  float4 ba = ((const float4*)bias)[cg * 2];
  float4 bb = ((const float4*)bias)[cg * 2 + 1];
#pragma unroll
  for (int i = 0; i < 8; ++i) {
    int gr = row0 + rg * 8 + i;
    if (gr < M) {
      float4 oa, ob;
      oa.x = fmaxf(acc[i][0] + ba.x, 0.f); oa.y = fmaxf(acc[i][1] + ba.y, 0.f);
      oa.z = fmaxf(acc[i][2] + ba.z, 0.f); oa.w = fmaxf(acc[i][3] + ba.w, 0.f);
      ob.x = fmaxf(acc[i][4] + bb.x, 0.f); ob.y = fmaxf(acc[i][5] + bb.y, 0.f);
      ob.z = fmaxf(acc[i][6] + bb.z, 0.f); ob.w = fmaxf(acc[i][7] + bb.w, 0.f);
      ((float4*)Out)[gr * 32 + cg * 2] = oa;
      ((float4*)Out)[gr * 32 + cg * 2 + 1] = ob;
    }
  }
}

__global__ __launch_bounds__(128) void k_cls(const float* __restrict__ t, const float* __restrict__ Wr2,
                                             const float* __restrict__ br2, float* __restrict__ out) {
  int gi = blockIdx.x;
  __shared__ float row[128];
  row[threadIdx.x] = t[gi * 128 + threadIdx.x];
  __syncthreads();
  if (threadIdx.x < NC) {
    float acc = br2[threadIdx.x];
    for (int k = 0; k < 128; ++k) acc = fmaf(row[k], Wr2[k * NC + threadIdx.x], acc);
    out[gi * NC + threadIdx.x] = acc;
  }
}

// ---------------- launch ----------------

extern "C" void kernel_launch(void* const* d_in, const int* in_sizes, int n_in,
                              void* d_out, int out_size, void* d_ws, size_t ws_size,
                              hipStream_t stream) {
  const float* x     = (const float*)d_in[0];
  const int*   src   = (const int*)d_in[1];
  const int*   dst   = (const int*)d_in[2];
  const int*   batch = (const int*)d_in[3];
  const float* W_enc = (const float*)d_in[4];
  const float* b_enc = (const float*)d_in[5];
  const float* W1 = (const float*)d_in[6],  *b1 = (const float*)d_in[7];
  const float* W2 = (const float*)d_in[8],  *b2 = (const float*)d_in[9];
  const float* W3 = (const float*)d_in[10], *b3 = (const float*)d_in[11];
  const float* Wr1 = (const float*)d_in[12], *br1 = (const float*)d_in[13];
  const float* Wr2 = (const float*)d_in[14], *br2 = (const float*)d_in[15];
  float* out = (float*)d_out;

  char* ws = (char*)d_ws;
  size_t off = 0;
  auto alloc = [&](size_t bytes) {
    void* p = ws + off;
    off = (off + bytes + 255) & ~(size_t)255;
    return p;
  };
  unsigned short* h   = (unsigned short*)alloc((size_t)NN * 128 * 2);
  unsigned short* hp  = (unsigned short*)alloc((size_t)NN * 128 * 2);
  unsigned short* WtE = (unsigned short*)alloc(128 * 128 * 2);
  unsigned short* Wt1 = (unsigned short*)alloc(128 * 128 * 2);
  unsigned short* Wt2 = (unsigned short*)alloc(128 * 128 * 2);
  unsigned short* Wt3 = (unsigned short*)alloc(128 * 128 * 2);
  int*   deg      = (int*)alloc((size_t)NN * 4);
  float* dinv     = (float*)alloc((size_t)NN * 4);
  int*   offs     = (int*)alloc((size_t)NN * 4);
  int*   cursor   = (int*)alloc((size_t)NN * 4);
  int*   bsum     = (int*)alloc(512 * 4);
  int2*  csr      = (int2*)alloc((size_t)NE * 8);
  float* g        = (float*)alloc((size_t)NG * 128 * 4);
  float* t1       = (float*)alloc((size_t)NG * 128 * 4);

  hipMemsetAsync(deg, 0, (size_t)NN * 4, stream);
  hipMemsetAsync(cursor, 0, (size_t)NN * 4, stream);

  int nbN = (NN + 255) / 256;   // 391
  int nbE = (NE + 255) / 256;   // 6250
  k_deg<<<nbE, 256, 0, stream>>>(dst, deg);
  k_dinv<<<nbN, 256, 0, stream>>>(deg, dinv);
  k_bsum<<<nbN, 256, 0, stream>>>(deg, bsum);
  k_scan_par<<<1, 512, 0, stream>>>(bsum, nbN);
  k_offs<<<nbN, 256, 0, stream>>>(deg, bsum, offs);
  k_csr<<<nbE, 256, 0, stream>>>(src, dst, offs, cursor, dinv, csr);

  k_wt<<<64, 256, 0, stream>>>(W_enc, WtE);
  k_wt<<<64, 256, 0, stream>>>(W1, Wt1);
  k_wt<<<64, 256, 0, stream>>>(W2, Wt2);
  k_wt<<<64, 256, 0, stream>>>(W3, Wt3);

  int gM = (NN + 127) / 128;  // 782
  k_gemm_mfma<1, 0, 1><<<gM, 256, 0, stream>>>(x, WtE, b_enc, h, NN);

  const unsigned short* Wts[3] = {Wt1, Wt2, Wt3};
  const float* bs[3] = {b1, b2, b3};
  int gA = (NN + 3) / 4;  // 25000
  for (int L = 0; L < 3; ++L) {
    k_gemm_mfma<0, 0, 0><<<gM, 256, 0, stream>>>(h, Wts[L], nullptr, hp, NN);
    k_agg2<<<gA, 256, 0, stream>>>(hp, offs, deg, dinv, csr, bs[L], h, 0);
    k_agg2<<<gA, 256, 0, stream>>>(hp, offs, deg, dinv, csr, bs[L], h, 1);
  }

  k_pool<<<NG, 128, 0, stream>>>(h, batch, g);
  k_gemm_f32<<<(NG + 127) / 128, 256, 0, stream>>>(g, Wr1, br1, t1, NG);
  k_cls<<<NG, 128, 0, stream>>>(t1, Wr2, br2, out);
}

// Round 5
// 579.564 us; speedup vs baseline: 1.1453x; 1.1453x over previous
//
#include <hip/hip_runtime.h>
#include <hip/hip_bf16.h>

#define NN 100000
#define NE 1600000
#define NG 512
#define NC 10

typedef __attribute__((ext_vector_type(8))) short bf16x8;
typedef __attribute__((ext_vector_type(4))) float f32x4;

__device__ __forceinline__ float bflo(unsigned u) { return __uint_as_float(u << 16); }
__device__ __forceinline__ float bfhi(unsigned u) { return __uint_as_float(u & 0xffff0000u); }
__device__ __forceinline__ unsigned short f2bf(float f) {
  unsigned u = __float_as_uint(f);
  unsigned r = u + 0x7fffu + ((u >> 16) & 1u);
  return (unsigned short)(r >> 16);
}

// ---------------- preprocessing: degree, dinv, CSR (src-only) by dst ----------------

__global__ __launch_bounds__(256) void k_deg(const int* __restrict__ dst, int* __restrict__ deg) {
  int e = blockIdx.x * 256 + threadIdx.x;
  if (e < NE) atomicAdd(&deg[dst[e]], 1);
}

__global__ __launch_bounds__(256) void k_dinv(const int* __restrict__ deg, float* __restrict__ dinv) {
  int i = blockIdx.x * 256 + threadIdx.x;
  if (i < NN) dinv[i] = rsqrtf((float)deg[i] + 1.0f);
}

__global__ __launch_bounds__(256) void k_bsum(const int* __restrict__ deg, int* __restrict__ bsum) {
  __shared__ int sm[256];
  int i = blockIdx.x * 256 + threadIdx.x;
  sm[threadIdx.x] = (i < NN) ? deg[i] : 0;
  __syncthreads();
  for (int o = 128; o > 0; o >>= 1) {
    if (threadIdx.x < o) sm[threadIdx.x] += sm[threadIdx.x + o];
    __syncthreads();
  }
  if (threadIdx.x == 0) bsum[blockIdx.x] = sm[0];
}

__global__ __launch_bounds__(512) void k_scan_par(int* bsum, int nb) {
  __shared__ int sm[512];
  int t = threadIdx.x;
  int orig = (t < nb) ? bsum[t] : 0;
  sm[t] = orig;
  __syncthreads();
  for (int o = 1; o < 512; o <<= 1) {
    int v = (t >= o) ? sm[t - o] : 0;
    __syncthreads();
    sm[t] += v;
    __syncthreads();
  }
  if (t < nb) bsum[t] = sm[t] - orig;  // exclusive
}

__global__ __launch_bounds__(256) void k_offs(const int* __restrict__ deg, const int* __restrict__ bsum,
                                              int* __restrict__ offs) {
  __shared__ int sm[256];
  int i = blockIdx.x * 256 + threadIdx.x;
  int v = (i < NN) ? deg[i] : 0;
  sm[threadIdx.x] = v;
  __syncthreads();
  for (int o = 1; o < 256; o <<= 1) {
    int t = (threadIdx.x >= o) ? sm[threadIdx.x - o] : 0;
    __syncthreads();
    sm[threadIdx.x] += t;
    __syncthreads();
  }
  if (i < NN) offs[i] = bsum[blockIdx.x] + sm[threadIdx.x] - v;  // exclusive
}

__global__ __launch_bounds__(256) void k_csr(const int* __restrict__ src, const int* __restrict__ dst,
                                             const int* __restrict__ offs, int* __restrict__ cursor,
                                             int* __restrict__ csr_src) {
  int e = blockIdx.x * 256 + threadIdx.x;
  if (e < NE) {
    int s = src[e], d = dst[e];
    int p = offs[d] + atomicAdd(&cursor[d], 1);
    csr_src[p] = s;
  }
}

// 4 weight transposes in one launch: Wt[c][k] = bf16(W[k][c])
__global__ __launch_bounds__(256) void k_wt4(const float* __restrict__ Wa, const float* __restrict__ Wb,
                                             const float* __restrict__ Wc, const float* __restrict__ Wd,
                                             unsigned short* __restrict__ Ta, unsigned short* __restrict__ Tb,
                                             unsigned short* __restrict__ Tc, unsigned short* __restrict__ Td) {
  int w = blockIdx.x >> 6;
  const float* W = (w == 0) ? Wa : (w == 1) ? Wb : (w == 2) ? Wc : Wd;
  unsigned short* T = (w == 0) ? Ta : (w == 1) ? Tb : (w == 2) ? Tc : Td;
  int idx = (blockIdx.x & 63) * 256 + threadIdx.x;
  int k = idx >> 7, c = idx & 127;
  T[c * 128 + k] = f2bf(W[k * 128 + c]);
}

// ---------------- bf16 MFMA GEMM: Out[M,128] = (A[M,128] @ W[128,128]) [*dinv_row] ----------------

template<int ADD_BIAS, int RELU, int SRC_F32, int SCALE_ROW>
__global__ __launch_bounds__(256) void k_gemm_mfma(const void* __restrict__ Ap,
                                                   const unsigned short* __restrict__ Wt,
                                                   const float* __restrict__ bias,
                                                   const float* __restrict__ dinv,
                                                   unsigned short* __restrict__ Out, int M) {
  __shared__ uint4 Al4[2048];  // 128 rows x 16 chunks (16B = 8 bf16)
  __shared__ uint4 Wl4[2048];
  int row0 = blockIdx.x * 128;
  const uint4* W16 = (const uint4*)Wt;
#pragma unroll
  for (int it = 0; it < 8; ++it) {
    int idx = it * 256 + threadIdx.x;
    int r = idx >> 4, c = idx & 15;
    int gr = row0 + r;
    uint4 v = make_uint4(0, 0, 0, 0);
    if (gr < M) {
      if (SRC_F32) {
        const float4* Af = (const float4*)Ap;
        float4 f0 = Af[(size_t)gr * 32 + c * 2];
        float4 f1 = Af[(size_t)gr * 32 + c * 2 + 1];
        v.x = (unsigned)f2bf(f0.x) | ((unsigned)f2bf(f0.y) << 16);
        v.y = (unsigned)f2bf(f0.z) | ((unsigned)f2bf(f0.w) << 16);
        v.z = (unsigned)f2bf(f1.x) | ((unsigned)f2bf(f1.y) << 16);
        v.w = (unsigned)f2bf(f1.z) | ((unsigned)f2bf(f1.w) << 16);
      } else {
        v = ((const uint4*)Ap)[(size_t)gr * 16 + c];
      }
    }
    Al4[r * 16 + (c ^ (r & 15))] = v;
    Wl4[r * 16 + (c ^ (r & 15))] = W16[idx];
  }
  __syncthreads();

  int lane = threadIdx.x & 63;
  int wid = threadIdx.x >> 6;
  int wr = wid >> 1, wc = wid & 1;
  int lr = lane & 15, kb = lane >> 4;

  f32x4 acc[4][4] = {};
#pragma unroll
  for (int ks = 0; ks < 4; ++ks) {
    int c = ks * 4 + kb;
    bf16x8 af[4], bfr[4];
#pragma unroll
    for (int i = 0; i < 4; ++i) {
      int ar = wr * 64 + i * 16 + lr;
      af[i] = *(const bf16x8*)&Al4[ar * 16 + (c ^ lr)];
      int bc = wc * 64 + i * 16 + lr;
      bfr[i] = *(const bf16x8*)&Wl4[bc * 16 + (c ^ lr)];
    }
#pragma unroll
    for (int i = 0; i < 4; ++i)
#pragma unroll
      for (int n = 0; n < 4; ++n)
        acc[i][n] = __builtin_amdgcn_mfma_f32_16x16x32_bf16(af[i], bfr[n], acc[i][n], 0, 0, 0);
  }

  float bcol[4];
  if (ADD_BIAS) {
#pragma unroll
    for (int n = 0; n < 4; ++n) bcol[n] = bias[wc * 64 + n * 16 + lr];
  }
#pragma unroll
  for (int i = 0; i < 4; ++i) {
    int rbase = row0 + wr * 64 + i * 16 + kb * 4;
#pragma unroll
    for (int n = 0; n < 4; ++n) {
      int col = wc * 64 + n * 16 + lr;
#pragma unroll
      for (int j = 0; j < 4; ++j) {
        int gr = rbase + j;
        if (gr < M) {
          float v = acc[i][n][j];
          if (ADD_BIAS) v += bcol[n];
          if (RELU) v = fmaxf(v, 0.f);
          if (SCALE_ROW) v *= dinv[gr];
          Out[(size_t)gr * 128 + col] = f2bf(v);
        }
      }
    }
  }
}

// ---------------- edge aggregation: wave/node, src-only records, pre-scaled hs ----------------
// hs = (h@W) * dinv (from GEMM).  out[i] = relu( (sum_e hs[src] + hs[i]) * dinv_i + b )

__global__ __launch_bounds__(256) void k_agg(const unsigned short* __restrict__ hs,
                                             const int* __restrict__ offs, const int* __restrict__ deg,
                                             const float* __restrict__ dinv,
                                             const int* __restrict__ csr_src,
                                             const float* __restrict__ bias,
                                             unsigned short* __restrict__ out) {
  int node = blockIdx.x * 4 + (threadIdx.x >> 6);
  if (node >= NN) return;
  int l = threadIdx.x & 63;
  const unsigned* hs32 = (const unsigned*)hs;  // 64 u32 per row
  float di = dinv[node];
  unsigned v = hs32[(size_t)node * 64 + l];
  float ax = bflo(v), ay = bfhi(v);  // self term hs[i]
  int p0 = offs[node], n = deg[node];
  int p = 0;
  for (; p + 8 <= n; p += 8) {
    int s0 = csr_src[p0 + p],     s1 = csr_src[p0 + p + 1];
    int s2 = csr_src[p0 + p + 2], s3 = csr_src[p0 + p + 3];
    int s4 = csr_src[p0 + p + 4], s5 = csr_src[p0 + p + 5];
    int s6 = csr_src[p0 + p + 6], s7 = csr_src[p0 + p + 7];
    unsigned u0 = hs32[(size_t)s0 * 64 + l], u1 = hs32[(size_t)s1 * 64 + l];
    unsigned u2 = hs32[(size_t)s2 * 64 + l], u3 = hs32[(size_t)s3 * 64 + l];
    unsigned u4 = hs32[(size_t)s4 * 64 + l], u5 = hs32[(size_t)s5 * 64 + l];
    unsigned u6 = hs32[(size_t)s6 * 64 + l], u7 = hs32[(size_t)s7 * 64 + l];
    ax += bflo(u0) + bflo(u1) + bflo(u2) + bflo(u3) + bflo(u4) + bflo(u5) + bflo(u6) + bflo(u7);
    ay += bfhi(u0) + bfhi(u1) + bfhi(u2) + bfhi(u3) + bfhi(u4) + bfhi(u5) + bfhi(u6) + bfhi(u7);
  }
  for (; p < n; ++p) {
    int s0 = csr_src[p0 + p];
    unsigned u0 = hs32[(size_t)s0 * 64 + l];
    ax += bflo(u0);
    ay += bfhi(u0);
  }
  float2 b2 = ((const float2*)bias)[l];
  ax = fmaxf(fmaf(ax, di, b2.x), 0.f);
  ay = fmaxf(fmaf(ay, di, b2.y), 0.f);
  ((unsigned*)out)[(size_t)node * 64 + l] = (unsigned)f2bf(ax) | ((unsigned)f2bf(ay) << 16);
}

// ---------------- pooling: 4 row-streams x 64 u32-lanes per graph ----------------

__device__ __forceinline__ int lowerb(const int* a, int n, int key) {
  int lo = 0, hi = n;
  while (lo < hi) {
    int mid = (lo + hi) >> 1;
    if (a[mid] < key) lo = mid + 1; else hi = mid;
  }
  return lo;
}

__global__ __launch_bounds__(256) void k_pool(const unsigned short* __restrict__ h, const int* __restrict__ batch,
                                              float* __restrict__ g) {
  __shared__ float sx[4][64];
  __shared__ float sy[4][64];
  int gi = blockIdx.x;
  int col = threadIdx.x & 63;
  int rp = threadIdx.x >> 6;
  int lo = lowerb(batch, NN, gi), hi = lowerb(batch, NN, gi + 1);
  const unsigned* h32 = (const unsigned*)h;
  float ax = 0.f, ay = 0.f;
  for (int i = lo + rp; i < hi; i += 4) {
    unsigned u = h32[(size_t)i * 64 + col];
    ax += bflo(u);
    ay += bfhi(u);
  }
  sx[rp][col] = ax;
  sy[rp][col] = ay;
  __syncthreads();
  if (rp == 0) {
    ax = sx[0][col] + sx[1][col] + sx[2][col] + sx[3][col];
    ay = sy[0][col] + sy[1][col] + sy[2][col] + sy[3][col];
    ((float2*)g)[gi * 64 + col] = make_float2(ax, ay);
  }
}

// small f32 GEMM for t1 = relu(g @ Wr1 + br1): M=512
__global__ __launch_bounds__(256) void k_gemm_f32(const float* __restrict__ A, const float* __restrict__ W,
                                                  const float* __restrict__ bias, float* __restrict__ Out,
                                                  int M) {
  __shared__ float4 Wl[128 * 32];
  __shared__ float4 Xl[128 * 32];
  const float4* W4 = (const float4*)W;
  for (int i = threadIdx.x; i < 4096; i += 256) Wl[i] = W4[i];
  int row0 = blockIdx.x * 128;
  const float4* A4 = (const float4*)A;
  for (int i = threadIdx.x; i < 4096; i += 256) {
    int r = i >> 5, g = i & 31;
    int gr = row0 + r;
    float4 v = make_float4(0.f, 0.f, 0.f, 0.f);
    if (gr < M) v = A4[gr * 32 + g];
    Xl[r * 32 + (g ^ ((r >> 3) & 7))] = v;
  }
  __syncthreads();

  int cg = threadIdx.x & 15;
  int rg = threadIdx.x >> 4;
  int swz = rg & 7;
  float acc[8][8] = {};
  for (int g = 0; g < 32; ++g) {
    float4 xv[8];
#pragma unroll
    for (int i = 0; i < 8; ++i) xv[i] = Xl[(rg * 8 + i) * 32 + (g ^ swz)];
#pragma unroll
    for (int kk = 0; kk < 4; ++kk) {
      float4 wa = Wl[(g * 4 + kk) * 32 + cg * 2];
      float4 wb = Wl[(g * 4 + kk) * 32 + cg * 2 + 1];
#pragma unroll
      for (int i = 0; i < 8; ++i) {
        float x = (kk == 0) ? xv[i].x : (kk == 1) ? xv[i].y : (kk == 2) ? xv[i].z : xv[i].w;
        acc[i][0] = fmaf(x, wa.x, acc[i][0]);
        acc[i][1] = fmaf(x, wa.y, acc[i][1]);
        acc[i][2] = fmaf(x, wa.z, acc[i][2]);
        acc[i][3] = fmaf(x, wa.w, acc[i][3]);
        acc[i][4] = fmaf(x, wb.x, acc[i][4]);
        acc[i][5] = fmaf(x, wb.y, acc[i][5]);
        acc[i][6] = fmaf(x, wb.z, acc[i][6]);
        acc[i][7] = fmaf(x, wb.w, acc[i][7]);
      }
    }
  }
  float4 ba = ((const float4*)bias)[cg * 2];
  float4 bb = ((const float4*)bias)[cg * 2 + 1];
#pragma unroll
  for (int i = 0; i < 8; ++i) {
    int gr = row0 + rg * 8 + i;
    if (gr < M) {
      float4 oa, ob;
      oa.x = fmaxf(acc[i][0] + ba.x, 0.f); oa.y = fmaxf(acc[i][1] + ba.y, 0.f);
      oa.z = fmaxf(acc[i][2] + ba.z, 0.f); oa.w = fmaxf(acc[i][3] + ba.w, 0.f);
      ob.x = fmaxf(acc[i][4] + bb.x, 0.f); ob.y = fmaxf(acc[i][5] + bb.y, 0.f);
      ob.z = fmaxf(acc[i][6] + bb.z, 0.f); ob.w = fmaxf(acc[i][7] + bb.w, 0.f);
      ((float4*)Out)[gr * 32 + cg * 2] = oa;
      ((float4*)Out)[gr * 32 + cg * 2 + 1] = ob;
    }
  }
}

__global__ __launch_bounds__(128) void k_cls(const float* __restrict__ t, const float* __restrict__ Wr2,
                                             const float* __restrict__ br2, float* __restrict__ out) {
  int gi = blockIdx.x;
  __shared__ float row[128];
  row[threadIdx.x] = t[gi * 128 + threadIdx.x];
  __syncthreads();
  if (threadIdx.x < NC) {
    float acc = br2[threadIdx.x];
    for (int k = 0; k < 128; ++k) acc = fmaf(row[k], Wr2[k * NC + threadIdx.x], acc);
    out[gi * NC + threadIdx.x] = acc;
  }
}

// ---------------- launch ----------------

extern "C" void kernel_launch(void* const* d_in, const int* in_sizes, int n_in,
                              void* d_out, int out_size, void* d_ws, size_t ws_size,
                              hipStream_t stream) {
  const float* x     = (const float*)d_in[0];
  const int*   src   = (const int*)d_in[1];
  const int*   dst   = (const int*)d_in[2];
  const int*   batch = (const int*)d_in[3];
  const float* W_enc = (const float*)d_in[4];
  const float* b_enc = (const float*)d_in[5];
  const float* W1 = (const float*)d_in[6],  *b1 = (const float*)d_in[7];
  const float* W2 = (const float*)d_in[8],  *b2 = (const float*)d_in[9];
  const float* W3 = (const float*)d_in[10], *b3 = (const float*)d_in[11];
  const float* Wr1 = (const float*)d_in[12], *br1 = (const float*)d_in[13];
  const float* Wr2 = (const float*)d_in[14], *br2 = (const float*)d_in[15];
  float* out = (float*)d_out;

  char* ws = (char*)d_ws;
  size_t off = 0;
  auto alloc = [&](size_t bytes) {
    void* p = ws + off;
    off = (off + bytes + 255) & ~(size_t)255;
    return p;
  };
  unsigned short* h   = (unsigned short*)alloc((size_t)NN * 128 * 2);
  unsigned short* hs  = (unsigned short*)alloc((size_t)NN * 128 * 2);
  unsigned short* WtE = (unsigned short*)alloc(128 * 128 * 2);
  unsigned short* Wt1 = (unsigned short*)alloc(128 * 128 * 2);
  unsigned short* Wt2 = (unsigned short*)alloc(128 * 128 * 2);
  unsigned short* Wt3 = (unsigned short*)alloc(128 * 128 * 2);
  int*   deg      = (int*)alloc((size_t)NN * 4);
  float* dinv     = (float*)alloc((size_t)NN * 4);
  int*   offs     = (int*)alloc((size_t)NN * 4);
  int*   cursor   = (int*)alloc((size_t)NN * 4);
  int*   bsum     = (int*)alloc(512 * 4);
  int*   csr_src  = (int*)alloc((size_t)NE * 4);
  float* g        = (float*)alloc((size_t)NG * 128 * 4);
  float* t1       = (float*)alloc((size_t)NG * 128 * 4);

  hipMemsetAsync(deg, 0, (size_t)NN * 4, stream);
  hipMemsetAsync(cursor, 0, (size_t)NN * 4, stream);

  int nbN = (NN + 255) / 256;   // 391
  int nbE = (NE + 255) / 256;   // 6250
  k_deg<<<nbE, 256, 0, stream>>>(dst, deg);
  k_dinv<<<nbN, 256, 0, stream>>>(deg, dinv);
  k_bsum<<<nbN, 256, 0, stream>>>(deg, bsum);
  k_scan_par<<<1, 512, 0, stream>>>(bsum, nbN);
  k_offs<<<nbN, 256, 0, stream>>>(deg, bsum, offs);
  k_csr<<<nbE, 256, 0, stream>>>(src, dst, offs, cursor, csr_src);

  k_wt4<<<256, 256, 0, stream>>>(W_enc, W1, W2, W3, WtE, Wt1, Wt2, Wt3);

  int gM = (NN + 127) / 128;  // 782
  k_gemm_mfma<1, 0, 1, 0><<<gM, 256, 0, stream>>>(x, WtE, b_enc, nullptr, h, NN);

  const unsigned short* Wts[3] = {Wt1, Wt2, Wt3};
  const float* bs[3] = {b1, b2, b3};
  int gA = (NN + 3) / 4;  // 25000
  for (int L = 0; L < 3; ++L) {
    k_gemm_mfma<0, 0, 0, 1><<<gM, 256, 0, stream>>>(h, Wts[L], nullptr, dinv, hs, NN);
    k_agg<<<gA, 256, 0, stream>>>(hs, offs, deg, dinv, csr_src, bs[L], h);
  }

  k_pool<<<NG, 256, 0, stream>>>(h, batch, g);
  k_gemm_f32<<<(NG + 127) / 128, 256, 0, stream>>>(g, Wr1, br1, t1, NG);
  k_cls<<<NG, 128, 0, stream>>>(t1, Wr2, br2, out);
}

// Round 6
// 528.296 us; speedup vs baseline: 1.2565x; 1.0970x over previous
//
#include <hip/hip_runtime.h>
#include <hip/hip_bf16.h>

#define NN 100000
#define NE 1600000
#define NG 512
#define NC 10
#define NBINS 98          // 1024 nodes per bin
#define EPB 4096          // edges per pass-1 block

typedef __attribute__((ext_vector_type(8))) short bf16x8;
typedef __attribute__((ext_vector_type(4))) float f32x4;

__device__ __forceinline__ float bflo(unsigned u) { return __uint_as_float(u << 16); }
__device__ __forceinline__ float bfhi(unsigned u) { return __uint_as_float(u & 0xffff0000u); }
__device__ __forceinline__ unsigned short f2bf(float f) {
  unsigned u = __float_as_uint(f);
  unsigned r = u + 0x7fffu + ((u >> 16) & 1u);
  return (unsigned short)(r >> 16);
}

// ---------------- preprocessing ----------------

__global__ __launch_bounds__(256) void k_deg(const int* __restrict__ dst, int* __restrict__ deg) {
  int e = blockIdx.x * 256 + threadIdx.x;
  if (e < NE) atomicAdd(&deg[dst[e]], 1);
}

// dinv + per-256-block deg sums in one kernel
__global__ __launch_bounds__(256) void k_dinv_bsum(const int* __restrict__ deg, float* __restrict__ dinv,
                                                   int* __restrict__ bsum) {
  __shared__ int sm[256];
  int i = blockIdx.x * 256 + threadIdx.x;
  int v = 0;
  if (i < NN) {
    v = deg[i];
    dinv[i] = rsqrtf((float)v + 1.0f);
  }
  sm[threadIdx.x] = v;
  __syncthreads();
  for (int o = 128; o > 0; o >>= 1) {
    if (threadIdx.x < o) sm[threadIdx.x] += sm[threadIdx.x + o];
    __syncthreads();
  }
  if (threadIdx.x == 0) bsum[blockIdx.x] = sm[0];
}

__global__ __launch_bounds__(512) void k_scan_par(int* bsum, int nb) {
  __shared__ int sm[512];
  int t = threadIdx.x;
  int orig = (t < nb) ? bsum[t] : 0;
  sm[t] = orig;
  __syncthreads();
  for (int o = 1; o < 512; o <<= 1) {
    int v = (t >= o) ? sm[t - o] : 0;
    __syncthreads();
    sm[t] += v;
    __syncthreads();
  }
  if (t < nb) bsum[t] = sm[t] - orig;  // exclusive
}

__global__ __launch_bounds__(256) void k_offs(const int* __restrict__ deg, const int* __restrict__ bsum,
                                              int* __restrict__ offs) {
  __shared__ int sm[256];
  int i = blockIdx.x * 256 + threadIdx.x;
  int v = (i < NN) ? deg[i] : 0;
  sm[threadIdx.x] = v;
  __syncthreads();
  for (int o = 1; o < 256; o <<= 1) {
    int t = (threadIdx.x >= o) ? sm[threadIdx.x - o] : 0;
    __syncthreads();
    sm[threadIdx.x] += t;
    __syncthreads();
  }
  if (i < NN) offs[i] = bsum[blockIdx.x] + sm[threadIdx.x] - v;  // exclusive
}

__global__ __launch_bounds__(128) void k_bininit(const int* __restrict__ offs, int* __restrict__ binCursor) {
  int t = threadIdx.x;
  if (t < NBINS) binCursor[t] = offs[t * 1024];
}

// pass 1: bin-group edges, burst-write (src,dst) pairs into per-bin segments of stage[]
__global__ __launch_bounds__(256) void k_binp1(const int* __restrict__ src, const int* __restrict__ dst,
                                               int* __restrict__ binCursor, uint2* __restrict__ stage) {
  __shared__ uint2 sstage[EPB];        // 32 KB
  __shared__ int cnt[NBINS];
  __shared__ int pre[NBINS + 1];
  __shared__ int base[NBINS];
  __shared__ int lcur[NBINS];
  int t = threadIdx.x;
  for (int i = t; i < NBINS; i += 256) { cnt[i] = 0; lcur[i] = 0; }
  __syncthreads();
  int e0 = blockIdx.x * EPB;
  int mybin[16];
  uint2 mypair[16];
#pragma unroll
  for (int i = 0; i < 16; ++i) {
    int e = e0 + i * 256 + t;
    if (e < NE) {
      int s = src[e], d = dst[e];
      mybin[i] = d >> 10;
      mypair[i] = make_uint2((unsigned)s, (unsigned)d);
      atomicAdd(&cnt[mybin[i]], 1);
    } else {
      mybin[i] = -1;
    }
  }
  __syncthreads();
  if (t == 0) {
    int run = 0;
    for (int b = 0; b < NBINS; ++b) { pre[b] = run; run += cnt[b]; }
    pre[NBINS] = run;
  }
  __syncthreads();
  if (t < NBINS && cnt[t] > 0) base[t] = atomicAdd(&binCursor[t], cnt[t]);
  __syncthreads();
#pragma unroll
  for (int i = 0; i < 16; ++i) {
    if (mybin[i] >= 0) {
      int r = atomicAdd(&lcur[mybin[i]], 1);
      sstage[pre[mybin[i]] + r] = mypair[i];
    }
  }
  __syncthreads();
  int total = pre[NBINS];
  for (int sidx = t; sidx < total; sidx += 256) {
    int lo = 0, hi = NBINS - 1;             // largest b with pre[b] <= sidx
    while (lo < hi) { int mid = (lo + hi + 1) >> 1; if (pre[mid] <= sidx) lo = mid; else hi = mid - 1; }
    stage[base[lo] + (sidx - pre[lo])] = sstage[sidx];
  }
}

// pass 2: one block owns one bin; scatter confined to ~65KB window (L2-merged)
__global__ __launch_bounds__(256) void k_binp2(const uint2* __restrict__ stage, const int* __restrict__ offs,
                                               int* __restrict__ csr_src) {
  __shared__ int lcur[1024];
  __shared__ int loff[1024];
  int b = blockIdx.x;
  int n0 = b * 1024;
  int t = threadIdx.x;
  for (int i = t; i < 1024; i += 256) {
    lcur[i] = 0;
    int node = n0 + i;
    loff[i] = (node < NN) ? offs[node] : NE;
  }
  __syncthreads();
  int e0 = loff[0];
  int n1 = n0 + 1024;
  int e1 = (n1 >= NN) ? NE : offs[n1];
  for (int j = e0 + t; j < e1; j += 256) {
    uint2 p = stage[j];
    int li = (int)p.y - n0;
    int r = atomicAdd(&lcur[li], 1);
    csr_src[loff[li] + r] = (int)p.x;
  }
}

// 4 weight transposes in one launch: Wt[c][k] = bf16(W[k][c])
__global__ __launch_bounds__(256) void k_wt4(const float* __restrict__ Wa, const float* __restrict__ Wb,
                                             const float* __restrict__ Wc, const float* __restrict__ Wd,
                                             unsigned short* __restrict__ Ta, unsigned short* __restrict__ Tb,
                                             unsigned short* __restrict__ Tc, unsigned short* __restrict__ Td) {
  int w = blockIdx.x >> 6;
  const float* W = (w == 0) ? Wa : (w == 1) ? Wb : (w == 2) ? Wc : Wd;
  unsigned short* T = (w == 0) ? Ta : (w == 1) ? Tb : (w == 2) ? Tc : Td;
  int idx = (blockIdx.x & 63) * 256 + threadIdx.x;
  int k = idx >> 7, c = idx & 127;
  T[c * 128 + k] = f2bf(W[k * 128 + c]);
}

// ---------------- bf16 MFMA GEMM: Out[M,128] = (A[M,128] @ W[128,128]) [*dinv_row] ----------------

template<int ADD_BIAS, int RELU, int SRC_F32, int SCALE_ROW>
__global__ __launch_bounds__(256) void k_gemm_mfma(const void* __restrict__ Ap,
                                                   const unsigned short* __restrict__ Wt,
                                                   const float* __restrict__ bias,
                                                   const float* __restrict__ dinv,
                                                   unsigned short* __restrict__ Out, int M) {
  __shared__ uint4 Al4[2048];  // 128 rows x 16 chunks (16B = 8 bf16)
  __shared__ uint4 Wl4[2048];
  int row0 = blockIdx.x * 128;
  const uint4* W16 = (const uint4*)Wt;
#pragma unroll
  for (int it = 0; it < 8; ++it) {
    int idx = it * 256 + threadIdx.x;
    int r = idx >> 4, c = idx & 15;
    int gr = row0 + r;
    uint4 v = make_uint4(0, 0, 0, 0);
    if (gr < M) {
      if (SRC_F32) {
        const float4* Af = (const float4*)Ap;
        float4 f0 = Af[(size_t)gr * 32 + c * 2];
        float4 f1 = Af[(size_t)gr * 32 + c * 2 + 1];
        v.x = (unsigned)f2bf(f0.x) | ((unsigned)f2bf(f0.y) << 16);
        v.y = (unsigned)f2bf(f0.z) | ((unsigned)f2bf(f0.w) << 16);
        v.z = (unsigned)f2bf(f1.x) | ((unsigned)f2bf(f1.y) << 16);
        v.w = (unsigned)f2bf(f1.z) | ((unsigned)f2bf(f1.w) << 16);
      } else {
        v = ((const uint4*)Ap)[(size_t)gr * 16 + c];
      }
    }
    Al4[r * 16 + (c ^ (r & 15))] = v;
    Wl4[r * 16 + (c ^ (r & 15))] = W16[idx];
  }
  __syncthreads();

  int lane = threadIdx.x & 63;
  int wid = threadIdx.x >> 6;
  int wr = wid >> 1, wc = wid & 1;
  int lr = lane & 15, kb = lane >> 4;

  f32x4 acc[4][4] = {};
#pragma unroll
  for (int ks = 0; ks < 4; ++ks) {
    int c = ks * 4 + kb;
    bf16x8 af[4], bfr[4];
#pragma unroll
    for (int i = 0; i < 4; ++i) {
      int ar = wr * 64 + i * 16 + lr;
      af[i] = *(const bf16x8*)&Al4[ar * 16 + (c ^ lr)];
      int bc = wc * 64 + i * 16 + lr;
      bfr[i] = *(const bf16x8*)&Wl4[bc * 16 + (c ^ lr)];
    }
#pragma unroll
    for (int i = 0; i < 4; ++i)
#pragma unroll
      for (int n = 0; n < 4; ++n)
        acc[i][n] = __builtin_amdgcn_mfma_f32_16x16x32_bf16(af[i], bfr[n], acc[i][n], 0, 0, 0);
  }

  float bcol[4];
  if (ADD_BIAS) {
#pragma unroll
    for (int n = 0; n < 4; ++n) bcol[n] = bias[wc * 64 + n * 16 + lr];
  }
#pragma unroll
  for (int i = 0; i < 4; ++i) {
    int rbase = row0 + wr * 64 + i * 16 + kb * 4;
#pragma unroll
    for (int n = 0; n < 4; ++n) {
      int col = wc * 64 + n * 16 + lr;
#pragma unroll
      for (int j = 0; j < 4; ++j) {
        int gr = rbase + j;
        if (gr < M) {
          float v = acc[i][n][j];
          if (ADD_BIAS) v += bcol[n];
          if (RELU) v = fmaxf(v, 0.f);
          if (SCALE_ROW) v *= dinv[gr];
          Out[(size_t)gr * 128 + col] = f2bf(v);
        }
      }
    }
  }
}

// ---------------- edge aggregation: wave/node, src-only records, pre-scaled hs ----------------
// hs = (h@W) * dinv (from GEMM).  out[i] = relu( (sum_e hs[src] + hs[i]) * dinv_i + b )

__global__ __launch_bounds__(256) void k_agg(const unsigned short* __restrict__ hs,
                                             const int* __restrict__ offs, const int* __restrict__ deg,
                                             const float* __restrict__ dinv,
                                             const int* __restrict__ csr_src,
                                             const float* __restrict__ bias,
                                             unsigned short* __restrict__ out) {
  int node = blockIdx.x * 4 + (threadIdx.x >> 6);
  if (node >= NN) return;
  int l = threadIdx.x & 63;
  const unsigned* hs32 = (const unsigned*)hs;  // 64 u32 per row
  float di = dinv[node];
  unsigned v = hs32[(size_t)node * 64 + l];
  float ax = bflo(v), ay = bfhi(v);  // self term hs[i]
  int p0 = offs[node], n = deg[node];
  int p = 0;
  for (; p + 8 <= n; p += 8) {
    int s0 = csr_src[p0 + p],     s1 = csr_src[p0 + p + 1];
    int s2 = csr_src[p0 + p + 2], s3 = csr_src[p0 + p + 3];
    int s4 = csr_src[p0 + p + 4], s5 = csr_src[p0 + p + 5];
    int s6 = csr_src[p0 + p + 6], s7 = csr_src[p0 + p + 7];
    unsigned u0 = hs32[(size_t)s0 * 64 + l], u1 = hs32[(size_t)s1 * 64 + l];
    unsigned u2 = hs32[(size_t)s2 * 64 + l], u3 = hs32[(size_t)s3 * 64 + l];
    unsigned u4 = hs32[(size_t)s4 * 64 + l], u5 = hs32[(size_t)s5 * 64 + l];
    unsigned u6 = hs32[(size_t)s6 * 64 + l], u7 = hs32[(size_t)s7 * 64 + l];
    ax += bflo(u0) + bflo(u1) + bflo(u2) + bflo(u3) + bflo(u4) + bflo(u5) + bflo(u6) + bflo(u7);
    ay += bfhi(u0) + bfhi(u1) + bfhi(u2) + bfhi(u3) + bfhi(u4) + bfhi(u5) + bfhi(u6) + bfhi(u7);
  }
  for (; p < n; ++p) {
    int s0 = csr_src[p0 + p];
    unsigned u0 = hs32[(size_t)s0 * 64 + l];
    ax += bflo(u0);
    ay += bfhi(u0);
  }
  float2 b2 = ((const float2*)bias)[l];
  ax = fmaxf(fmaf(ax, di, b2.x), 0.f);
  ay = fmaxf(fmaf(ay, di, b2.y), 0.f);
  ((unsigned*)out)[(size_t)node * 64 + l] = (unsigned)f2bf(ax) | ((unsigned)f2bf(ay) << 16);
}

// ---------------- pooling: 4 row-streams x 64 u32-lanes per graph ----------------

__device__ __forceinline__ int lowerb(const int* a, int n, int key) {
  int lo = 0, hi = n;
  while (lo < hi) {
    int mid = (lo + hi) >> 1;
    if (a[mid] < key) lo = mid + 1; else hi = mid;
  }
  return lo;
}

__global__ __launch_bounds__(256) void k_pool(const unsigned short* __restrict__ h, const int* __restrict__ batch,
                                              float* __restrict__ g) {
  __shared__ float sx[4][64];
  __shared__ float sy[4][64];
  int gi = blockIdx.x;
  int col = threadIdx.x & 63;
  int rp = threadIdx.x >> 6;
  int lo = lowerb(batch, NN, gi), hi = lowerb(batch, NN, gi + 1);
  const unsigned* h32 = (const unsigned*)h;
  float ax = 0.f, ay = 0.f;
  for (int i = lo + rp; i < hi; i += 4) {
    unsigned u = h32[(size_t)i * 64 + col];
    ax += bflo(u);
    ay += bfhi(u);
  }
  sx[rp][col] = ax;
  sy[rp][col] = ay;
  __syncthreads();
  if (rp == 0) {
    ax = sx[0][col] + sx[1][col] + sx[2][col] + sx[3][col];
    ay = sy[0][col] + sy[1][col] + sy[2][col] + sy[3][col];
    ((float2*)g)[gi * 64 + col] = make_float2(ax, ay);
  }
}

// small f32 GEMM for t1 = relu(g @ Wr1 + br1): M=512
__global__ __launch_bounds__(256) void k_gemm_f32(const float* __restrict__ A, const float* __restrict__ W,
                                                  const float* __restrict__ bias, float* __restrict__ Out,
                                                  int M) {
  __shared__ float4 Wl[128 * 32];
  __shared__ float4 Xl[128 * 32];
  const float4* W4 = (const float4*)W;
  for (int i = threadIdx.x; i < 4096; i += 256) Wl[i] = W4[i];
  int row0 = blockIdx.x * 128;
  const float4* A4 = (const float4*)A;
  for (int i = threadIdx.x; i < 4096; i += 256) {
    int r = i >> 5, g = i & 31;
    int gr = row0 + r;
    float4 v = make_float4(0.f, 0.f, 0.f, 0.f);
    if (gr < M) v = A4[gr * 32 + g];
    Xl[r * 32 + (g ^ ((r >> 3) & 7))] = v;
  }
  __syncthreads();

  int cg = threadIdx.x & 15;
  int rg = threadIdx.x >> 4;
  int swz = rg & 7;
  float acc[8][8] = {};
  for (int g = 0; g < 32; ++g) {
    float4 xv[8];
#pragma unroll
    for (int i = 0; i < 8; ++i) xv[i] = Xl[(rg * 8 + i) * 32 + (g ^ swz)];
#pragma unroll
    for (int kk = 0; kk < 4; ++kk) {
      float4 wa = Wl[(g * 4 + kk) * 32 + cg * 2];
      float4 wb = Wl[(g * 4 + kk) * 32 + cg * 2 + 1];
#pragma unroll
      for (int i = 0; i < 8; ++i) {
        float x = (kk == 0) ? xv[i].x : (kk == 1) ? xv[i].y : (kk == 2) ? xv[i].z : xv[i].w;
        acc[i][0] = fmaf(x, wa.x, acc[i][0]);
        acc[i][1] = fmaf(x, wa.y, acc[i][1]);
        acc[i][2] = fmaf(x, wa.z, acc[i][2]);
        acc[i][3] = fmaf(x, wa.w, acc[i][3]);
        acc[i][4] = fmaf(x, wb.x, acc[i][4]);
        acc[i][5] = fmaf(x, wb.y, acc[i][5]);
        acc[i][6] = fmaf(x, wb.z, acc[i][6]);
        acc[i][7] = fmaf(x, wb.w, acc[i][7]);
      }
    }
  }
  float4 ba = ((const float4*)bias)[cg * 2];
  float4 bb = ((const float4*)bias)[cg * 2 + 1];
#pragma unroll
  for (int i = 0; i < 8; ++i) {
    int gr = row0 + rg * 8 + i;
    if (gr < M) {
      float4 oa, ob;
      oa.x = fmaxf(acc[i][0] + ba.x, 0.f); oa.y = fmaxf(acc[i][1] + ba.y, 0.f);
      oa.z = fmaxf(acc[i][2] + ba.z, 0.f); oa.w = fmaxf(acc[i][3] + ba.w, 0.f);
      ob.x = fmaxf(acc[i][4] + bb.x, 0.f); ob.y = fmaxf(acc[i][5] + bb.y, 0.f);
      ob.z = fmaxf(acc[i][6] + bb.z, 0.f); ob.w = fmaxf(acc[i][7] + bb.w, 0.f);
      ((float4*)Out)[gr * 32 + cg * 2] = oa;
      ((float4*)Out)[gr * 32 + cg * 2 + 1] = ob;
    }
  }
}

__global__ __launch_bounds__(128) void k_cls(const float* __restrict__ t, const float* __restrict__ Wr2,
                                             const float* __restrict__ br2, float* __restrict__ out) {
  int gi = blockIdx.x;
  __shared__ float row[128];
  row[threadIdx.x] = t[gi * 128 + threadIdx.x];
  __syncthreads();
  if (threadIdx.x < NC) {
    float acc = br2[threadIdx.x];
    for (int k = 0; k < 128; ++k) acc = fmaf(row[k], Wr2[k * NC + threadIdx.x], acc);
    out[gi * NC + threadIdx.x] = acc;
  }
}

// ---------------- launch ----------------

extern "C" void kernel_launch(void* const* d_in, const int* in_sizes, int n_in,
                              void* d_out, int out_size, void* d_ws, size_t ws_size,
                              hipStream_t stream) {
  const float* x     = (const float*)d_in[0];
  const int*   src   = (const int*)d_in[1];
  const int*   dst   = (const int*)d_in[2];
  const int*   batch = (const int*)d_in[3];
  const float* W_enc = (const float*)d_in[4];
  const float* b_enc = (const float*)d_in[5];
  const float* W1 = (const float*)d_in[6],  *b1 = (const float*)d_in[7];
  const float* W2 = (const float*)d_in[8],  *b2 = (const float*)d_in[9];
  const float* W3 = (const float*)d_in[10], *b3 = (const float*)d_in[11];
  const float* Wr1 = (const float*)d_in[12], *br1 = (const float*)d_in[13];
  const float* Wr2 = (const float*)d_in[14], *br2 = (const float*)d_in[15];
  float* out = (float*)d_out;

  char* ws = (char*)d_ws;
  size_t off = 0;
  auto alloc = [&](size_t bytes) {
    void* p = ws + off;
    off = (off + bytes + 255) & ~(size_t)255;
    return p;
  };
  unsigned short* h   = (unsigned short*)alloc((size_t)NN * 128 * 2);
  unsigned short* hs  = (unsigned short*)alloc((size_t)NN * 128 * 2);
  unsigned short* WtE = (unsigned short*)alloc(128 * 128 * 2);
  unsigned short* Wt1 = (unsigned short*)alloc(128 * 128 * 2);
  unsigned short* Wt2 = (unsigned short*)alloc(128 * 128 * 2);
  unsigned short* Wt3 = (unsigned short*)alloc(128 * 128 * 2);
  int*   deg      = (int*)alloc((size_t)NN * 4);
  float* dinv     = (float*)alloc((size_t)NN * 4);
  int*   offs     = (int*)alloc((size_t)NN * 4);
  int*   bsum     = (int*)alloc(512 * 4);
  int*   binCursor= (int*)alloc(NBINS * 4);
  int*   csr_src  = (int*)alloc((size_t)NE * 4);
  uint2* stage    = (uint2*)alloc((size_t)NE * 8);
  float* g        = (float*)alloc((size_t)NG * 128 * 4);
  float* t1       = (float*)alloc((size_t)NG * 128 * 4);

  hipMemsetAsync(deg, 0, (size_t)NN * 4, stream);

  int nbN = (NN + 255) / 256;   // 391
  int nbE = (NE + 255) / 256;   // 6250
  k_deg<<<nbE, 256, 0, stream>>>(dst, deg);
  k_dinv_bsum<<<nbN, 256, 0, stream>>>(deg, dinv, bsum);
  k_scan_par<<<1, 512, 0, stream>>>(bsum, nbN);
  k_offs<<<nbN, 256, 0, stream>>>(deg, bsum, offs);
  k_bininit<<<1, 128, 0, stream>>>(offs, binCursor);
  k_binp1<<<(NE + EPB - 1) / EPB, 256, 0, stream>>>(src, dst, binCursor, stage);
  k_binp2<<<NBINS, 256, 0, stream>>>(stage, offs, csr_src);

  k_wt4<<<256, 256, 0, stream>>>(W_enc, W1, W2, W3, WtE, Wt1, Wt2, Wt3);

  int gM = (NN + 127) / 128;  // 782
  k_gemm_mfma<1, 0, 1, 0><<<gM, 256, 0, stream>>>(x, WtE, b_enc, nullptr, h, NN);

  const unsigned short* Wts[3] = {Wt1, Wt2, Wt3};
  const float* bs[3] = {b1, b2, b3};
  int gA = (NN + 3) / 4;  // 25000
  for (int L = 0; L < 3; ++L) {
    k_gemm_mfma<0, 0, 0, 1><<<gM, 256, 0, stream>>>(h, Wts[L], nullptr, dinv, hs, NN);
    k_agg<<<gA, 256, 0, stream>>>(hs, offs, deg, dinv, csr_src, bs[L], h);
  }

  k_pool<<<NG, 256, 0, stream>>>(h, batch, g);
  k_gemm_f32<<<(NG + 127) / 128, 256, 0, stream>>>(g, Wr1, br1, t1, NG);
  k_cls<<<NG, 128, 0, stream>>>(t1, Wr2, br2, out);
}

// Round 7
// 436.066 us; speedup vs baseline: 1.5222x; 1.2115x over previous
//
#include <hip/hip_runtime.h>
#include <hip/hip_bf16.h>

#define NN 100000
#define NE 1600000
#define NG 512
#define NC 10
#define NBINS 196         // 512 nodes per bin
#define BINCAP 10240      // per-bin edge capacity (mean 8192, ~22 sigma headroom)
#define EPB 4096          // edges per pass-1 block

typedef __attribute__((ext_vector_type(8))) short bf16x8;
typedef __attribute__((ext_vector_type(4))) float f32x4;
typedef int int4a __attribute__((ext_vector_type(4), aligned(4)));

__device__ __forceinline__ float bflo(unsigned u) { return __uint_as_float(u << 16); }
__device__ __forceinline__ float bfhi(unsigned u) { return __uint_as_float(u & 0xffff0000u); }
__device__ __forceinline__ unsigned short f2bf(float f) {
  unsigned u = __float_as_uint(f);
  unsigned r = u + 0x7fffu + ((u >> 16) & 1u);
  return (unsigned short)(r >> 16);
}

// ---------------- binned CSR build (no global deg pass needed) ----------------

__global__ __launch_bounds__(256) void k_bininit(int* __restrict__ binCursor) {
  int t = blockIdx.x * 256 + threadIdx.x;
  if (t < NBINS) binCursor[t] = t * BINCAP;
}

// pass 1: bin-group edges in LDS, burst-write (src,dst) pairs into per-bin stage segments
__global__ __launch_bounds__(256) void k_binp1(const int* __restrict__ src, const int* __restrict__ dst,
                                               int* __restrict__ binCursor, uint2* __restrict__ stage) {
  __shared__ uint2 sstage[EPB];        // 32 KB
  __shared__ int cnt[NBINS];
  __shared__ int pre[NBINS];
  __shared__ int base[NBINS];
  __shared__ int lcur[NBINS];
  int t = threadIdx.x;
  for (int i = t; i < NBINS; i += 256) { cnt[i] = 0; lcur[i] = 0; }
  __syncthreads();
  int e0 = blockIdx.x * EPB;
  int mybin[16];
  uint2 mypair[16];
#pragma unroll
  for (int i = 0; i < 16; ++i) {
    int e = e0 + i * 256 + t;
    if (e < NE) {
      int s = src[e], d = dst[e];
      mybin[i] = d >> 9;
      mypair[i] = make_uint2((unsigned)s, (unsigned)d);
      atomicAdd(&cnt[mybin[i]], 1);
    } else {
      mybin[i] = -1;
    }
  }
  __syncthreads();
  if (t == 0) {
    int run = 0;
    for (int b = 0; b < NBINS; ++b) { pre[b] = run; run += cnt[b]; }
  }
  __syncthreads();
  if (t < NBINS && cnt[t] > 0) base[t] = atomicAdd(&binCursor[t], cnt[t]);
  __syncthreads();
#pragma unroll
  for (int i = 0; i < 16; ++i) {
    if (mybin[i] >= 0) {
      int r = atomicAdd(&lcur[mybin[i]], 1);
      sstage[pre[mybin[i]] + r] = mypair[i];
    }
  }
  __syncthreads();
  int total = NE - e0; if (total > EPB) total = EPB;
  for (int sidx = t; sidx < total; sidx += 256) {
    uint2 pr = sstage[sidx];
    int b = (int)(pr.y >> 9);
    stage[base[b] + (sidx - pre[b])] = pr;
  }
}

// pass 2: one block owns one 512-node bin; derive deg/dinv/offs; scatter csr within L2-sized window
__global__ __launch_bounds__(256) void k_binp2(const uint2* __restrict__ stage, const int* __restrict__ binCursor,
                                               int* __restrict__ csr_src, int* __restrict__ offs,
                                               int* __restrict__ deg, float* __restrict__ dinv) {
  __shared__ int ldeg[512];
  __shared__ int loff[512];
  __shared__ int part[256];
  int b = blockIdx.x;
  int t = threadIdx.x;
  int n0 = b << 9;
  int sbase = b * BINCAP;
  int cnt = binCursor[b] - sbase;
  for (int i = t; i < 512; i += 256) ldeg[i] = 0;
  __syncthreads();
  for (int j = t; j < cnt; j += 256) {
    int d = (int)stage[sbase + j].y;
    atomicAdd(&ldeg[d - n0], 1);
  }
  __syncthreads();
  int i2 = t * 2;
  int a0 = ldeg[i2], a1 = ldeg[i2 + 1];
  int s = a0 + a1;
  part[t] = s;
  __syncthreads();
  for (int o = 1; o < 256; o <<= 1) {
    int v = (t >= o) ? part[t - o] : 0;
    __syncthreads();
    part[t] += v;
    __syncthreads();
  }
  int ex = part[t] - s;  // exclusive
  loff[i2] = ex;
  loff[i2 + 1] = ex + a0;
  int nd0 = n0 + i2, nd1 = n0 + i2 + 1;
  if (nd0 < NN) { offs[nd0] = sbase + ex;      deg[nd0] = a0; dinv[nd0] = rsqrtf((float)a0 + 1.0f); }
  if (nd1 < NN) { offs[nd1] = sbase + ex + a0; deg[nd1] = a1; dinv[nd1] = rsqrtf((float)a1 + 1.0f); }
  ldeg[i2] = 0; ldeg[i2 + 1] = 0;   // reuse as cursors
  __syncthreads();
  for (int j = t; j < cnt; j += 256) {
    uint2 p = stage[sbase + j];
    int li = (int)p.y - n0;
    int r = atomicAdd(&ldeg[li], 1);
    csr_src[sbase + loff[li] + r] = (int)p.x;
  }
}

// 4 weight transposes in one launch: Wt[c][k] = bf16(W[k][c])
__global__ __launch_bounds__(256) void k_wt4(const float* __restrict__ Wa, const float* __restrict__ Wb,
                                             const float* __restrict__ Wc, const float* __restrict__ Wd,
                                             unsigned short* __restrict__ Ta, unsigned short* __restrict__ Tb,
                                             unsigned short* __restrict__ Tc, unsigned short* __restrict__ Td) {
  int w = blockIdx.x >> 6;
  const float* W = (w == 0) ? Wa : (w == 1) ? Wb : (w == 2) ? Wc : Wd;
  unsigned short* T = (w == 0) ? Ta : (w == 1) ? Tb : (w == 2) ? Tc : Td;
  int idx = (blockIdx.x & 63) * 256 + threadIdx.x;
  int k = idx >> 7, c = idx & 127;
  T[c * 128 + k] = f2bf(W[k * 128 + c]);
}

// ---------------- bf16 MFMA GEMM: Out[M,128] = (A[M,128] @ W[128,128]) [*dinv_row] ----------------

template<int ADD_BIAS, int RELU, int SRC_F32, int SCALE_ROW>
__global__ __launch_bounds__(256) void k_gemm_mfma(const void* __restrict__ Ap,
                                                   const unsigned short* __restrict__ Wt,
                                                   const float* __restrict__ bias,
                                                   const float* __restrict__ dinv,
                                                   unsigned short* __restrict__ Out, int M) {
  __shared__ uint4 Al4[2048];  // 128 rows x 16 chunks (16B = 8 bf16)
  __shared__ uint4 Wl4[2048];
  int row0 = blockIdx.x * 128;
  const uint4* W16 = (const uint4*)Wt;
#pragma unroll
  for (int it = 0; it < 8; ++it) {
    int idx = it * 256 + threadIdx.x;
    int r = idx >> 4, c = idx & 15;
    int gr = row0 + r;
    uint4 v = make_uint4(0, 0, 0, 0);
    if (gr < M) {
      if (SRC_F32) {
        const float4* Af = (const float4*)Ap;
        float4 f0 = Af[(size_t)gr * 32 + c * 2];
        float4 f1 = Af[(size_t)gr * 32 + c * 2 + 1];
        v.x = (unsigned)f2bf(f0.x) | ((unsigned)f2bf(f0.y) << 16);
        v.y = (unsigned)f2bf(f0.z) | ((unsigned)f2bf(f0.w) << 16);
        v.z = (unsigned)f2bf(f1.x) | ((unsigned)f2bf(f1.y) << 16);
        v.w = (unsigned)f2bf(f1.z) | ((unsigned)f2bf(f1.w) << 16);
      } else {
        v = ((const uint4*)Ap)[(size_t)gr * 16 + c];
      }
    }
    Al4[r * 16 + (c ^ (r & 15))] = v;
    Wl4[r * 16 + (c ^ (r & 15))] = W16[idx];
  }
  __syncthreads();

  int lane = threadIdx.x & 63;
  int wid = threadIdx.x >> 6;
  int wr = wid >> 1, wc = wid & 1;
  int lr = lane & 15, kb = lane >> 4;

  f32x4 acc[4][4] = {};
#pragma unroll
  for (int ks = 0; ks < 4; ++ks) {
    int c = ks * 4 + kb;
    bf16x8 af[4], bfr[4];
#pragma unroll
    for (int i = 0; i < 4; ++i) {
      int ar = wr * 64 + i * 16 + lr;
      af[i] = *(const bf16x8*)&Al4[ar * 16 + (c ^ lr)];
      int bc = wc * 64 + i * 16 + lr;
      bfr[i] = *(const bf16x8*)&Wl4[bc * 16 + (c ^ lr)];
    }
#pragma unroll
    for (int i = 0; i < 4; ++i)
#pragma unroll
      for (int n = 0; n < 4; ++n)
        acc[i][n] = __builtin_amdgcn_mfma_f32_16x16x32_bf16(af[i], bfr[n], acc[i][n], 0, 0, 0);
  }

  float bcol[4];
  if (ADD_BIAS) {
#pragma unroll
    for (int n = 0; n < 4; ++n) bcol[n] = bias[wc * 64 + n * 16 + lr];
  }
#pragma unroll
  for (int i = 0; i < 4; ++i) {
    int rbase = row0 + wr * 64 + i * 16 + kb * 4;
#pragma unroll
    for (int n = 0; n < 4; ++n) {
      int col = wc * 64 + n * 16 + lr;
#pragma unroll
      for (int j = 0; j < 4; ++j) {
        int gr = rbase + j;
        if (gr < M) {
          float v = acc[i][n][j];
          if (ADD_BIAS) v += bcol[n];
          if (RELU) v = fmaxf(v, 0.f);
          if (SCALE_ROW) v *= dinv[gr];
          Out[(size_t)gr * 128 + col] = f2bf(v);
        }
      }
    }
  }
}

// ---------------- edge aggregation: wave/node, 16 gathers in flight ----------------
// hs = (h@W) * dinv (from GEMM).  out[i] = relu( (sum_e hs[src] + hs[i]) * dinv_i + b )

__global__ __launch_bounds__(256) void k_agg(const unsigned short* __restrict__ hs,
                                             const int* __restrict__ offs, const int* __restrict__ deg,
                                             const float* __restrict__ dinv,
                                             const int* __restrict__ csr_src,
                                             const float* __restrict__ bias,
                                             unsigned short* __restrict__ out) {
  int node = blockIdx.x * 4 + (threadIdx.x >> 6);
  if (node >= NN) return;
  int l = threadIdx.x & 63;
  const unsigned* hs32 = (const unsigned*)hs;  // 64 u32 per row
  float di = dinv[node];
  unsigned v = hs32[(size_t)node * 64 + l];
  float ax = bflo(v), ay = bfhi(v);  // self term hs[i]
  int p0 = offs[node], n = deg[node];
  int p = 0;
  for (; p + 16 <= n; p += 16) {
    const int* cp = csr_src + p0 + p;
    int4a i0 = *(const int4a*)cp;
    int4a i1 = *(const int4a*)(cp + 4);
    int4a i2 = *(const int4a*)(cp + 8);
    int4a i3 = *(const int4a*)(cp + 12);
    unsigned u0  = hs32[(size_t)i0.x * 64 + l], u1  = hs32[(size_t)i0.y * 64 + l];
    unsigned u2  = hs32[(size_t)i0.z * 64 + l], u3  = hs32[(size_t)i0.w * 64 + l];
    unsigned u4  = hs32[(size_t)i1.x * 64 + l], u5  = hs32[(size_t)i1.y * 64 + l];
    unsigned u6  = hs32[(size_t)i1.z * 64 + l], u7  = hs32[(size_t)i1.w * 64 + l];
    unsigned u8  = hs32[(size_t)i2.x * 64 + l], u9  = hs32[(size_t)i2.y * 64 + l];
    unsigned u10 = hs32[(size_t)i2.z * 64 + l], u11 = hs32[(size_t)i2.w * 64 + l];
    unsigned u12 = hs32[(size_t)i3.x * 64 + l], u13 = hs32[(size_t)i3.y * 64 + l];
    unsigned u14 = hs32[(size_t)i3.z * 64 + l], u15 = hs32[(size_t)i3.w * 64 + l];
    ax += bflo(u0) + bflo(u1) + bflo(u2) + bflo(u3) + bflo(u4) + bflo(u5) + bflo(u6) + bflo(u7)
        + bflo(u8) + bflo(u9) + bflo(u10) + bflo(u11) + bflo(u12) + bflo(u13) + bflo(u14) + bflo(u15);
    ay += bfhi(u0) + bfhi(u1) + bfhi(u2) + bfhi(u3) + bfhi(u4) + bfhi(u5) + bfhi(u6) + bfhi(u7)
        + bfhi(u8) + bfhi(u9) + bfhi(u10) + bfhi(u11) + bfhi(u12) + bfhi(u13) + bfhi(u14) + bfhi(u15);
  }
  for (; p + 8 <= n; p += 8) {
    const int* cp = csr_src + p0 + p;
    int4a i0 = *(const int4a*)cp;
    int4a i1 = *(const int4a*)(cp + 4);
    unsigned u0 = hs32[(size_t)i0.x * 64 + l], u1 = hs32[(size_t)i0.y * 64 + l];
    unsigned u2 = hs32[(size_t)i0.z * 64 + l], u3 = hs32[(size_t)i0.w * 64 + l];
    unsigned u4 = hs32[(size_t)i1.x * 64 + l], u5 = hs32[(size_t)i1.y * 64 + l];
    unsigned u6 = hs32[(size_t)i1.z * 64 + l], u7 = hs32[(size_t)i1.w * 64 + l];
    ax += bflo(u0) + bflo(u1) + bflo(u2) + bflo(u3) + bflo(u4) + bflo(u5) + bflo(u6) + bflo(u7);
    ay += bfhi(u0) + bfhi(u1) + bfhi(u2) + bfhi(u3) + bfhi(u4) + bfhi(u5) + bfhi(u6) + bfhi(u7);
  }
  for (; p < n; ++p) {
    int s0 = csr_src[p0 + p];
    unsigned u0 = hs32[(size_t)s0 * 64 + l];
    ax += bflo(u0);
    ay += bfhi(u0);
  }
  float2 b2 = ((const float2*)bias)[l];
  ax = fmaxf(fmaf(ax, di, b2.x), 0.f);
  ay = fmaxf(fmaf(ay, di, b2.y), 0.f);
  ((unsigned*)out)[(size_t)node * 64 + l] = (unsigned)f2bf(ax) | ((unsigned)f2bf(ay) << 16);
}

// ---------------- pooling: 4 row-streams x 64 u32-lanes per graph ----------------

__device__ __forceinline__ int lowerb(const int* a, int n, int key) {
  int lo = 0, hi = n;
  while (lo < hi) {
    int mid = (lo + hi) >> 1;
    if (a[mid] < key) lo = mid + 1; else hi = mid;
  }
  return lo;
}

__global__ __launch_bounds__(256) void k_pool(const unsigned short* __restrict__ h, const int* __restrict__ batch,
                                              float* __restrict__ g) {
  __shared__ float sx[4][64];
  __shared__ float sy[4][64];
  int gi = blockIdx.x;
  int col = threadIdx.x & 63;
  int rp = threadIdx.x >> 6;
  int lo = lowerb(batch, NN, gi), hi = lowerb(batch, NN, gi + 1);
  const unsigned* h32 = (const unsigned*)h;
  float ax = 0.f, ay = 0.f;
  for (int i = lo + rp; i < hi; i += 4) {
    unsigned u = h32[(size_t)i * 64 + col];
    ax += bflo(u);
    ay += bfhi(u);
  }
  sx[rp][col] = ax;
  sy[rp][col] = ay;
  __syncthreads();
  if (rp == 0) {
    ax = sx[0][col] + sx[1][col] + sx[2][col] + sx[3][col];
    ay = sy[0][col] + sy[1][col] + sy[2][col] + sy[3][col];
    ((float2*)g)[gi * 64 + col] = make_float2(ax, ay);
  }
}

// small f32 GEMM for t1 = relu(g @ Wr1 + br1): M=512
__global__ __launch_bounds__(256) void k_gemm_f32(const float* __restrict__ A, const float* __restrict__ W,
                                                  const float* __restrict__ bias, float* __restrict__ Out,
                                                  int M) {
  __shared__ float4 Wl[128 * 32];
  __shared__ float4 Xl[128 * 32];
  const float4* W4 = (const float4*)W;
  for (int i = threadIdx.x; i < 4096; i += 256) Wl[i] = W4[i];
  int row0 = blockIdx.x * 128;
  const float4* A4 = (const float4*)A;
  for (int i = threadIdx.x; i < 4096; i += 256) {
    int r = i >> 5, g = i & 31;
    int gr = row0 + r;
    float4 v = make_float4(0.f, 0.f, 0.f, 0.f);
    if (gr < M) v = A4[gr * 32 + g];
    Xl[r * 32 + (g ^ ((r >> 3) & 7))] = v;
  }
  __syncthreads();

  int cg = threadIdx.x & 15;
  int rg = threadIdx.x >> 4;
  int swz = rg & 7;
  float acc[8][8] = {};
  for (int g = 0; g < 32; ++g) {
    float4 xv[8];
#pragma unroll
    for (int i = 0; i < 8; ++i) xv[i] = Xl[(rg * 8 + i) * 32 + (g ^ swz)];
#pragma unroll
    for (int kk = 0; kk < 4; ++kk) {
      float4 wa = Wl[(g * 4 + kk) * 32 + cg * 2];
      float4 wb = Wl[(g * 4 + kk) * 32 + cg * 2 + 1];
#pragma unroll
      for (int i = 0; i < 8; ++i) {
        float x = (kk == 0) ? xv[i].x : (kk == 1) ? xv[i].y : (kk == 2) ? xv[i].z : xv[i].w;
        acc[i][0] = fmaf(x, wa.x, acc[i][0]);
        acc[i][1] = fmaf(x, wa.y, acc[i][1]);
        acc[i][2] = fmaf(x, wa.z, acc[i][2]);
        acc[i][3] = fmaf(x, wa.w, acc[i][3]);
        acc[i][4] = fmaf(x, wb.x, acc[i][4]);
        acc[i][5] = fmaf(x, wb.y, acc[i][5]);
        acc[i][6] = fmaf(x, wb.z, acc[i][6]);
        acc[i][7] = fmaf(x, wb.w, acc[i][7]);
      }
    }
  }
  float4 ba = ((const float4*)bias)[cg * 2];
  float4 bb = ((const float4*)bias)[cg * 2 + 1];
#pragma unroll
  for (int i = 0; i < 8; ++i) {
    int gr = row0 + rg * 8 + i;
    if (gr < M) {
      float4 oa, ob;
      oa.x = fmaxf(acc[i][0] + ba.x, 0.f); oa.y = fmaxf(acc[i][1] + ba.y, 0.f);
      oa.z = fmaxf(acc[i][2] + ba.z, 0.f); oa.w = fmaxf(acc[i][3] + ba.w, 0.f);
      ob.x = fmaxf(acc[i][4] + bb.x, 0.f); ob.y = fmaxf(acc[i][5] + bb.y, 0.f);
      ob.z = fmaxf(acc[i][6] + bb.z, 0.f); ob.w = fmaxf(acc[i][7] + bb.w, 0.f);
      ((float4*)Out)[gr * 32 + cg * 2] = oa;
      ((float4*)Out)[gr * 32 + cg * 2 + 1] = ob;
    }
  }
}

__global__ __launch_bounds__(128) void k_cls(const float* __restrict__ t, const float* __restrict__ Wr2,
                                             const float* __restrict__ br2, float* __restrict__ out) {
  int gi = blockIdx.x;
  __shared__ float row[128];
  row[threadIdx.x] = t[gi * 128 + threadIdx.x];
  __syncthreads();
  if (threadIdx.x < NC) {
    float acc = br2[threadIdx.x];
    for (int k = 0; k < 128; ++k) acc = fmaf(row[k], Wr2[k * NC + threadIdx.x], acc);
    out[gi * NC + threadIdx.x] = acc;
  }
}

// ---------------- launch ----------------

extern "C" void kernel_launch(void* const* d_in, const int* in_sizes, int n_in,
                              void* d_out, int out_size, void* d_ws, size_t ws_size,
                              hipStream_t stream) {
  const float* x     = (const float*)d_in[0];
  const int*   src   = (const int*)d_in[1];
  const int*   dst   = (const int*)d_in[2];
  const int*   batch = (const int*)d_in[3];
  const float* W_enc = (const float*)d_in[4];
  const float* b_enc = (const float*)d_in[5];
  const float* W1 = (const float*)d_in[6],  *b1 = (const float*)d_in[7];
  const float* W2 = (const float*)d_in[8],  *b2 = (const float*)d_in[9];
  const float* W3 = (const float*)d_in[10], *b3 = (const float*)d_in[11];
  const float* Wr1 = (const float*)d_in[12], *br1 = (const float*)d_in[13];
  const float* Wr2 = (const float*)d_in[14], *br2 = (const float*)d_in[15];
  float* out = (float*)d_out;

  char* ws = (char*)d_ws;
  size_t off = 0;
  auto alloc = [&](size_t bytes) {
    void* p = ws + off;
    off = (off + bytes + 255) & ~(size_t)255;
    return p;
  };
  unsigned short* h   = (unsigned short*)alloc((size_t)NN * 128 * 2);
  unsigned short* hs  = (unsigned short*)alloc((size_t)NN * 128 * 2);
  unsigned short* WtE = (unsigned short*)alloc(128 * 128 * 2);
  unsigned short* Wt1 = (unsigned short*)alloc(128 * 128 * 2);
  unsigned short* Wt2 = (unsigned short*)alloc(128 * 128 * 2);
  unsigned short* Wt3 = (unsigned short*)alloc(128 * 128 * 2);
  int*   deg      = (int*)alloc((size_t)NN * 4);
  float* dinv     = (float*)alloc((size_t)NN * 4);
  int*   offs     = (int*)alloc((size_t)NN * 4);
  int*   binCursor= (int*)alloc(NBINS * 4);
  int*   csr_src  = (int*)alloc((size_t)NBINS * BINCAP * 4);
  uint2* stage    = (uint2*)alloc((size_t)NBINS * BINCAP * 8);
  float* g        = (float*)alloc((size_t)NG * 128 * 4);
  float* t1       = (float*)alloc((size_t)NG * 128 * 4);

  k_bininit<<<1, 256, 0, stream>>>(binCursor);
  k_binp1<<<(NE + EPB - 1) / EPB, 256, 0, stream>>>(src, dst, binCursor, stage);
  k_binp2<<<NBINS, 256, 0, stream>>>(stage, binCursor, csr_src, offs, deg, dinv);

  k_wt4<<<256, 256, 0, stream>>>(W_enc, W1, W2, W3, WtE, Wt1, Wt2, Wt3);

  int gM = (NN + 127) / 128;  // 782
  k_gemm_mfma<1, 0, 1, 0><<<gM, 256, 0, stream>>>(x, WtE, b_enc, nullptr, h, NN);

  const unsigned short* Wts[3] = {Wt1, Wt2, Wt3};
  const float* bs[3] = {b1, b2, b3};
  int gA = (NN + 3) / 4;  // 25000
  for (int L = 0; L < 3; ++L) {
    k_gemm_mfma<0, 0, 0, 1><<<gM, 256, 0, stream>>>(h, Wts[L], nullptr, dinv, hs, NN);
    k_agg<<<gA, 256, 0, stream>>>(hs, offs, deg, dinv, csr_src, bs[L], h);
  }

  k_pool<<<NG, 256, 0, stream>>>(h, batch, g);
  k_gemm_f32<<<(NG + 127) / 128, 256, 0, stream>>>(g, Wr1, br1, t1, NG);
  k_cls<<<NG, 128, 0, stream>>>(t1, Wr2, br2, out);
}